// Round 3
// baseline (1910.585 us; speedup 1.0000x reference)
//
#include <hip/hip_runtime.h>
#include <math.h>

#define N_NODES 50000
#define DIM     128
#define N_EDGES 800000
#define N_UID   4096
#define NB      16
#define LN_EPS  1e-5f
#define RST     132   // padded LDS row stride (floats)

// ---------- CSR build ----------
__global__ __launch_bounds__(256) void deg_kernel(const int* __restrict__ dst, int* __restrict__ cnt) {
    int e = blockIdx.x * 256 + threadIdx.x;
    if (e < N_EDGES) atomicAdd(&cnt[dst[e]], 1);
}

__global__ __launch_bounds__(256) void scan1(const int* __restrict__ cnt, int* __restrict__ off,
                                             int* __restrict__ bsum) {
    __shared__ int sh[256];
    int t = threadIdx.x;
    int i = blockIdx.x * 256 + t;
    int v = (i < N_NODES) ? cnt[i] : 0;
    sh[t] = v;
    __syncthreads();
    for (int o = 1; o < 256; o <<= 1) {
        int x = (t >= o) ? sh[t - o] : 0;
        __syncthreads();
        sh[t] += x;
        __syncthreads();
    }
    if (i < N_NODES) off[i] = sh[t] - v;   // exclusive within block
    if (t == 255) bsum[blockIdx.x] = sh[255];
}

__global__ __launch_bounds__(256) void scan2(const int* __restrict__ bsum, int* __restrict__ bpre, int nblk) {
    __shared__ int sh[256];
    int t = threadIdx.x;
    int v = (t < nblk) ? bsum[t] : 0;
    sh[t] = v;
    __syncthreads();
    for (int o = 1; o < 256; o <<= 1) {
        int x = (t >= o) ? sh[t - o] : 0;
        __syncthreads();
        sh[t] += x;
        __syncthreads();
    }
    if (t < nblk) bpre[t] = sh[t] - v;     // exclusive
}

__global__ __launch_bounds__(256) void scan3(int* __restrict__ off, const int* __restrict__ bpre,
                                             int* __restrict__ cur) {
    int i = blockIdx.x * 256 + threadIdx.x;
    if (i < N_NODES) {
        int o = off[i] + bpre[blockIdx.x];
        off[i] = o;
        cur[i] = o;
    }
    if (i == 0) off[N_NODES] = N_EDGES;
}

// pack (src,dst) per CSR slot so the layer kernel reads one int2 per edge
__global__ __launch_bounds__(256) void fill_kernel(const int* __restrict__ src, const int* __restrict__ dst,
                                                   int* __restrict__ cur, int2* __restrict__ pack) {
    int e = blockIdx.x * 256 + threadIdx.x;
    if (e < N_EDGES) {
        int d = dst[e];
        int p = atomicAdd(&cur[d], 1);
        pack[p] = make_int2(src[e], d);
    }
}

// ---------- fused layer: edge-parallel aggregate + GEMM + LN + ELU ----------
// block = 256 threads, NB=16 nodes. 50000 = 16*3125 exactly.
__global__ __launch_bounds__(256) void layer_kernel(
    const float* __restrict__ fin, float* __restrict__ fout,
    const int* __restrict__ off, const int2* __restrict__ pack,
    const float* __restrict__ W, const float* __restrict__ bias,
    const float* __restrict__ gamma, const float* __restrict__ beta)
{
    __shared__ float xs[NB * RST];   // aggregated x, later reused for y
    __shared__ float ivs[NB];
    const int t = threadIdx.x;
    const int base = blockIdx.x * NB;

    // ---- init: self features into xs; per-node 1/(deg+1) ----
    {
        const int r = t >> 4, seg = t & 15;
        const float4* sp = (const float4*)(fin + (size_t)(base + r) * DIM + seg * 8);
        const float4 a = sp[0], b = sp[1];
        float* dp = xs + r * RST + seg * 8;
        ((float4*)dp)[0] = a;
        ((float4*)dp)[1] = b;
        if (t < NB) ivs[t] = 1.0f / (float)(off[base + t + 1] - off[base + t] + 1);
    }
    __syncthreads();

    // ---- edge-parallel aggregate: no serial per-node chains ----
    {
        const int lane = t & 31;
        const int stream = t >> 5;               // 0..7
        const int e0 = off[base], e1 = off[base + NB];
        int e = e0 + stream * 2;
        for (; e + 1 < e1; e += 16) {            // 2 edges per stream-iteration
            const int2 pA = pack[e];
            const int2 pB = pack[e + 1];
            const float* gA = fin + (size_t)pA.x * DIM + lane;
            const float* gB = fin + (size_t)pB.x * DIM + lane;
            const float a0 = gA[0], a1 = gA[32], a2 = gA[64], a3 = gA[96];
            const float b0 = gB[0], b1 = gB[32], b2 = gB[64], b3 = gB[96];
            float* qA = xs + (pA.y - base) * RST + lane;
            float* qB = xs + (pB.y - base) * RST + lane;
            atomicAdd(qA,      a0); atomicAdd(qA + 32, a1);
            atomicAdd(qA + 64, a2); atomicAdd(qA + 96, a3);
            atomicAdd(qB,      b0); atomicAdd(qB + 32, b1);
            atomicAdd(qB + 64, b2); atomicAdd(qB + 96, b3);
        }
        if (e < e1) {
            const int2 p = pack[e];
            const float* g = fin + (size_t)p.x * DIM + lane;
            float* q = xs + (p.y - base) * RST + lane;
            atomicAdd(q,      g[0]);  atomicAdd(q + 32, g[32]);
            atomicAdd(q + 64, g[64]); atomicAdd(q + 96, g[96]);
        }
    }
    __syncthreads();

    // ---- GEMM: y[j][c] = dot(W[c,:], x_raw[j,:]) * iv[j] + b[c] ----
    float acc[8];
    const int c = t & 127;
    const int h = t >> 7;
    {
        #pragma unroll
        for (int j = 0; j < 8; ++j) acc[j] = 0.0f;
        const float4* __restrict__ Wr = (const float4*)(W + (size_t)c * DIM);
        const float* __restrict__ xb = xs + h * 8 * RST;
        for (int k4 = 0; k4 < DIM / 4; ++k4) {
            const float4 w = Wr[k4];
            #pragma unroll
            for (int j = 0; j < 8; ++j) {
                const float4 xv = *((const float4*)(xb + j * RST + k4 * 4)); // wave-uniform broadcast
                acc[j] = fmaf(w.x, xv.x, acc[j]);
                acc[j] = fmaf(w.y, xv.y, acc[j]);
                acc[j] = fmaf(w.z, xv.z, acc[j]);
                acc[j] = fmaf(w.w, xv.w, acc[j]);
            }
        }
    }
    __syncthreads();   // all x reads done before overwriting xs with y
    {
        const float bv = bias[c];
        #pragma unroll
        for (int j = 0; j < 8; ++j)
            xs[(h * 8 + j) * RST + c] = acc[j] * ivs[h * 8 + j] + bv;
    }
    __syncthreads();

    // ---- LayerNorm + ELU; 16 threads per node, 8 dims each ----
    {
        const int j   = t >> 4;          // node 0..15
        const int seg = t & 15;          // 0..15
        const float* yr = xs + j * RST + seg * 8;
        const float4 a0 = ((const float4*)yr)[0];
        const float4 a1 = ((const float4*)yr)[1];
        float vs[8] = {a0.x, a0.y, a0.z, a0.w, a1.x, a1.y, a1.z, a1.w};
        float s = 0.0f, s2 = 0.0f;
        #pragma unroll
        for (int i = 0; i < 8; ++i) { s += vs[i]; s2 += vs[i] * vs[i]; }
        #pragma unroll
        for (int m = 1; m < 16; m <<= 1) {
            s  += __shfl_xor(s,  m);
            s2 += __shfl_xor(s2, m);
        }
        const float mu  = s * (1.0f / 128.0f);
        const float var = s2 * (1.0f / 128.0f) - mu * mu;
        const float rs  = rsqrtf(var + LN_EPS);
        const int n  = base + j;
        const int db = seg * 8;
        float ov[8];
        #pragma unroll
        for (int i = 0; i < 8; ++i) {
            const float z = (vs[i] - mu) * rs * gamma[db + i] + beta[db + i];
            ov[i] = (z > 0.0f) ? z : expm1f(z);
        }
        float4* op = (float4*)(fout + (size_t)n * DIM + db);
        op[0] = make_float4(ov[0], ov[1], ov[2], ov[3]);
        op[1] = make_float4(ov[4], ov[5], ov[6], ov[7]);
    }
}

// ---------- output gather ----------
__global__ __launch_bounds__(256) void gather_kernel(const float* __restrict__ fin,
                                                     const int* __restrict__ uid,
                                                     float* __restrict__ out) {
    int idx = blockIdx.x * 256 + threadIdx.x;   // float4 index
    int u = idx >> 5;
    int lane = idx & 31;
    if (u < N_UID) {
        int node = uid[u];
        ((float4*)out)[idx] = ((const float4*)(fin + (size_t)node * DIM))[lane];
    }
}

extern "C" void kernel_launch(void* const* d_in, const int* in_sizes, int n_in,
                              void* d_out, int out_size, void* d_ws, size_t ws_size,
                              hipStream_t stream) {
    const float* emb   = (const float*)d_in[0];
    const float* W     = (const float*)d_in[1];
    const float* bias  = (const float*)d_in[2];
    const float* gamma = (const float*)d_in[3];
    const float* beta  = (const float*)d_in[4];
    const int*   src   = (const int*)d_in[5];
    const int*   dst   = (const int*)d_in[6];
    const int*   uid   = (const int*)d_in[7];

    // workspace layout (~58 MB)
    float* A    = (float*)d_ws;                      // 50000*128
    float* B    = A + (size_t)N_NODES * DIM;         // 50000*128
    int*   cnt  = (int*)(B + (size_t)N_NODES * DIM); // 50000
    int*   off  = cnt + N_NODES;                     // 50001 (+pad)
    int*   cur  = off + (N_NODES + 4);               // 50000
    int*   bsum = cur + N_NODES;                     // 256
    int*   bpre = bsum + 256;                        // 256
    int2*  pack = (int2*)(bpre + 256);               // 800000 int2 (8B-aligned)

    hipMemsetAsync(cnt, 0, N_NODES * sizeof(int), stream);

    const int eblk = (N_EDGES + 255) / 256;          // 3125
    const int nblk = (N_NODES + 255) / 256;          // 196
    deg_kernel<<<eblk, 256, 0, stream>>>(dst, cnt);
    scan1<<<nblk, 256, 0, stream>>>(cnt, off, bsum);
    scan2<<<1, 256, 0, stream>>>(bsum, bpre, nblk);
    scan3<<<nblk, 256, 0, stream>>>(off, bpre, cur);
    fill_kernel<<<eblk, 256, 0, stream>>>(src, dst, cur, pack);

    const int lblocks = N_NODES / NB;                // 3125 exact
    layer_kernel<<<lblocks, 256, 0, stream>>>(emb, A, off, pack,
                                              W, bias, gamma, beta);
    layer_kernel<<<lblocks, 256, 0, stream>>>(A, B, off, pack,
                                              W + DIM * DIM, bias + DIM, gamma + DIM, beta + DIM);
    layer_kernel<<<lblocks, 256, 0, stream>>>(B, A, off, pack,
                                              W + 2 * DIM * DIM, bias + 2 * DIM, gamma + 2 * DIM, beta + 2 * DIM);

    gather_kernel<<<(N_UID * DIM / 4 + 255) / 256, 256, 0, stream>>>(A, uid, (float*)d_out);
}

// Round 4
// 439.438 us; speedup vs baseline: 4.3478x; 4.3478x over previous
//
#include <hip/hip_runtime.h>
#include <math.h>

#define N_NODES 50000
#define DIM     128
#define N_EDGES 800000
#define N_UID   4096
#define NB      8
#define LN_EPS  1e-5f
#define RST     132   // padded LDS row stride (floats)
#define CAP     1024  // staged CSR indices per block

// ---------- CSR build ----------
__global__ __launch_bounds__(256) void deg_kernel(const int* __restrict__ dst, int* __restrict__ cnt) {
    int e = blockIdx.x * 256 + threadIdx.x;
    if (e < N_EDGES) atomicAdd(&cnt[dst[e]], 1);
}

__global__ __launch_bounds__(256) void scan1(const int* __restrict__ cnt, int* __restrict__ off,
                                             int* __restrict__ bsum) {
    __shared__ int sh[256];
    int t = threadIdx.x;
    int i = blockIdx.x * 256 + t;
    int v = (i < N_NODES) ? cnt[i] : 0;
    sh[t] = v;
    __syncthreads();
    for (int o = 1; o < 256; o <<= 1) {
        int x = (t >= o) ? sh[t - o] : 0;
        __syncthreads();
        sh[t] += x;
        __syncthreads();
    }
    if (i < N_NODES) off[i] = sh[t] - v;   // exclusive within block
    if (t == 255) bsum[blockIdx.x] = sh[255];
}

__global__ __launch_bounds__(256) void scan2(const int* __restrict__ bsum, int* __restrict__ bpre, int nblk) {
    __shared__ int sh[256];
    int t = threadIdx.x;
    int v = (t < nblk) ? bsum[t] : 0;
    sh[t] = v;
    __syncthreads();
    for (int o = 1; o < 256; o <<= 1) {
        int x = (t >= o) ? sh[t - o] : 0;
        __syncthreads();
        sh[t] += x;
        __syncthreads();
    }
    if (t < nblk) bpre[t] = sh[t] - v;     // exclusive
}

__global__ __launch_bounds__(256) void scan3(int* __restrict__ off, const int* __restrict__ bpre,
                                             int* __restrict__ cur) {
    int i = blockIdx.x * 256 + threadIdx.x;
    if (i < N_NODES) {
        int o = off[i] + bpre[blockIdx.x];
        off[i] = o;
        cur[i] = o;
    }
    if (i == 0) off[N_NODES] = N_EDGES;
}

__global__ __launch_bounds__(256) void fill_kernel(const int* __restrict__ src, const int* __restrict__ dst,
                                                   int* __restrict__ cur, int* __restrict__ csr) {
    int e = blockIdx.x * 256 + threadIdx.x;
    if (e < N_EDGES) {
        int p = atomicAdd(&cur[dst[e]], 1);
        csr[p] = src[e];
    }
}

// ---------- fused layer: gather-aggregate + GEMM + LN + ELU ----------
// block = 256 threads, NB=8 node slots, one 32-lane stream per node.
// uidmap==nullptr: slot j handles node base+j, output row base+j of fout.
// uidmap!=nullptr: slot j handles node uidmap[base+j], output row base+j.
__global__ __launch_bounds__(256) void layer_kernel(
    const float* __restrict__ fin, float* __restrict__ fout,
    const int* __restrict__ off, const int* __restrict__ csr,
    const int* __restrict__ uidmap,
    const float* __restrict__ W, const float* __restrict__ bias,
    const float* __restrict__ gamma, const float* __restrict__ beta)
{
    __shared__ float xs[NB * RST];
    __shared__ float ivs[NB];
    __shared__ int   sidx[CAP];
    const int t    = threadIdx.x;
    const int base = blockIdx.x * NB;
    const int s    = t >> 5;          // stream / node slot 0..7
    const int lane = t & 31;          // float4 index within 512B row

    // ---- phase 0: node id, degree, CSR staging ----
    const int n  = uidmap ? uidmap[base + s] : (base + s);
    const int a0 = off[n], a1 = off[n + 1];
    if (lane == 0) ivs[s] = 1.0f / (float)(a1 - a0 + 1);

    int d0, d1, e0b = 0;
    bool fits = false;
    if (!uidmap) {
        e0b = off[base];
        const int cnt = off[base + NB] - e0b;
        fits = (cnt <= CAP);
        if (fits) {
            for (int i = t; i < cnt; i += 256) sidx[i] = csr[e0b + i];
        }
        d0 = a0 - e0b; d1 = a1 - e0b;
    } else {
        d0 = a0; d1 = a1;             // absolute indices into csr
    }

    float4 acc = ((const float4*)(fin + (size_t)n * DIM))[lane];  // self row
    __syncthreads();                  // sidx visible

    // ---- phase 1: gather-aggregate, 8 rows in flight, masked tail ----
    auto gath = [&](auto idxp, float4 a) -> float4 {
        for (int e = d0; e < d1; e += 8) {
            if (e + 8 <= d1) {
                const int i0 = idxp[e + 0], i1 = idxp[e + 1], i2 = idxp[e + 2], i3 = idxp[e + 3];
                const int i4 = idxp[e + 4], i5 = idxp[e + 5], i6 = idxp[e + 6], i7 = idxp[e + 7];
                const float4 v0 = ((const float4*)(fin + (size_t)i0 * DIM))[lane];
                const float4 v1 = ((const float4*)(fin + (size_t)i1 * DIM))[lane];
                const float4 v2 = ((const float4*)(fin + (size_t)i2 * DIM))[lane];
                const float4 v3 = ((const float4*)(fin + (size_t)i3 * DIM))[lane];
                const float4 v4 = ((const float4*)(fin + (size_t)i4 * DIM))[lane];
                const float4 v5 = ((const float4*)(fin + (size_t)i5 * DIM))[lane];
                const float4 v6 = ((const float4*)(fin + (size_t)i6 * DIM))[lane];
                const float4 v7 = ((const float4*)(fin + (size_t)i7 * DIM))[lane];
                a.x += ((v0.x + v1.x) + (v2.x + v3.x)) + ((v4.x + v5.x) + (v6.x + v7.x));
                a.y += ((v0.y + v1.y) + (v2.y + v3.y)) + ((v4.y + v5.y) + (v6.y + v7.y));
                a.z += ((v0.z + v1.z) + (v2.z + v3.z)) + ((v4.z + v5.z) + (v6.z + v7.z));
                a.w += ((v0.w + v1.w) + (v2.w + v3.w)) + ((v4.w + v5.w) + (v6.w + v7.w));
            } else {
                const int last = d1 - 1;   // masked 8-wide tail (clamped idx, 0/1 fma)
#define TAILK(k) {                                                              \
                const int  ik = idxp[(e + k <= last) ? (e + k) : last];         \
                const float4 vk = ((const float4*)(fin + (size_t)ik * DIM))[lane]; \
                const float mk = (e + k <= last) ? 1.0f : 0.0f;                 \
                a.x = fmaf(mk, vk.x, a.x); a.y = fmaf(mk, vk.y, a.y);           \
                a.z = fmaf(mk, vk.z, a.z); a.w = fmaf(mk, vk.w, a.w); }
                TAILK(0) TAILK(1) TAILK(2) TAILK(3)
                TAILK(4) TAILK(5) TAILK(6) TAILK(7)
#undef TAILK
            }
        }
        return a;
    };
    if (fits) acc = gath(sidx, acc);
    else      acc = gath(csr + e0b, acc);

    ((float4*)(xs + s * RST))[lane] = acc;   // raw sum (iv deferred to epilogue)
    __syncthreads();

    // ---- phase 2: GEMM y[j][c] = dot(W[c,:], x_raw[j,:]) ----
    const int c = t & 127;
    const int h = t >> 7;                    // node half: rows h*4 .. h*4+3
    float acc4[4];
    {
        #pragma unroll
        for (int j = 0; j < 4; ++j) acc4[j] = 0.0f;
        const float4* __restrict__ Wr = (const float4*)(W + (size_t)c * DIM);
        const float* xb = xs + h * 4 * RST;
        for (int k4 = 0; k4 < DIM / 4; ++k4) {
            const float4 w = Wr[k4];
            #pragma unroll
            for (int j = 0; j < 4; ++j) {
                const float4 xv = *((const float4*)(xb + j * RST + k4 * 4)); // broadcast
                acc4[j] = fmaf(w.x, xv.x, acc4[j]);
                acc4[j] = fmaf(w.y, xv.y, acc4[j]);
                acc4[j] = fmaf(w.z, xv.z, acc4[j]);
                acc4[j] = fmaf(w.w, xv.w, acc4[j]);
            }
        }
    }
    __syncthreads();                         // x reads done before overwrite
    {
        const float bv = bias[c];
        #pragma unroll
        for (int j = 0; j < 4; ++j)
            xs[(h * 4 + j) * RST + c] = acc4[j] * ivs[h * 4 + j] + bv;
    }
    __syncthreads();

    // ---- phase 3: LayerNorm + ELU; 32 threads per node, 4 dims each ----
    {
        const int j   = t >> 5;              // node slot 0..7
        const int seg = t & 31;              // 0..31
        const float4 v = *((const float4*)(xs + j * RST + seg * 4));
        float s1 = (v.x + v.y) + (v.z + v.w);
        float s2 = (v.x * v.x + v.y * v.y) + (v.z * v.z + v.w * v.w);
        #pragma unroll
        for (int m = 1; m < 32; m <<= 1) {
            s1 += __shfl_xor(s1, m);
            s2 += __shfl_xor(s2, m);
        }
        const float mu  = s1 * (1.0f / 128.0f);
        const float var = s2 * (1.0f / 128.0f) - mu * mu;
        const float rs  = rsqrtf(var + LN_EPS);
        const float4 g  = ((const float4*)gamma)[seg];
        const float4 bt = ((const float4*)beta)[seg];
        float4 o;
        float z;
        z = (v.x - mu) * rs * g.x + bt.x; o.x = (z > 0.0f) ? z : expm1f(z);
        z = (v.y - mu) * rs * g.y + bt.y; o.y = (z > 0.0f) ? z : expm1f(z);
        z = (v.z - mu) * rs * g.z + bt.z; o.z = (z > 0.0f) ? z : expm1f(z);
        z = (v.w - mu) * rs * g.w + bt.w; o.w = (z > 0.0f) ? z : expm1f(z);
        *((float4*)(fout + (size_t)(base + j) * DIM + seg * 4)) = o;
    }
}

extern "C" void kernel_launch(void* const* d_in, const int* in_sizes, int n_in,
                              void* d_out, int out_size, void* d_ws, size_t ws_size,
                              hipStream_t stream) {
    const float* emb   = (const float*)d_in[0];
    const float* W     = (const float*)d_in[1];
    const float* bias  = (const float*)d_in[2];
    const float* gamma = (const float*)d_in[3];
    const float* beta  = (const float*)d_in[4];
    const int*   src   = (const int*)d_in[5];
    const int*   dst   = (const int*)d_in[6];
    const int*   uid   = (const int*)d_in[7];

    // workspace layout (~55 MB)
    float* A    = (float*)d_ws;                      // 50000*128
    float* B    = A + (size_t)N_NODES * DIM;         // 50000*128
    int*   cnt  = (int*)(B + (size_t)N_NODES * DIM); // 50000
    int*   off  = cnt + N_NODES;                     // 50001 (+pad)
    int*   cur  = off + (N_NODES + 4);               // 50000
    int*   bsum = cur + N_NODES;                     // 256
    int*   bpre = bsum + 256;                        // 256
    int*   csr  = bpre + 256;                        // 800000

    hipMemsetAsync(cnt, 0, N_NODES * sizeof(int), stream);

    const int eblk = (N_EDGES + 255) / 256;          // 3125
    const int nblk = (N_NODES + 255) / 256;          // 196
    deg_kernel<<<eblk, 256, 0, stream>>>(dst, cnt);
    scan1<<<nblk, 256, 0, stream>>>(cnt, off, bsum);
    scan2<<<1, 256, 0, stream>>>(bsum, bpre, nblk);
    scan3<<<nblk, 256, 0, stream>>>(off, bpre, cur);
    fill_kernel<<<eblk, 256, 0, stream>>>(src, dst, cur, csr);

    const int lblocks = N_NODES / NB;                // 6250 exact
    layer_kernel<<<lblocks, 256, 0, stream>>>(emb, A, off, csr, nullptr,
                                              W, bias, gamma, beta);
    layer_kernel<<<lblocks, 256, 0, stream>>>(A, B, off, csr, nullptr,
                                              W + DIM * DIM, bias + DIM, gamma + DIM, beta + DIM);
    // layer 3: only the uid nodes are ever read — compute just those, into d_out
    layer_kernel<<<N_UID / NB, 256, 0, stream>>>(B, (float*)d_out, off, csr, uid,
                                                 W + 2 * DIM * DIM, bias + 2 * DIM,
                                                 gamma + 2 * DIM, beta + 2 * DIM);
}

// Round 5
// 432.460 us; speedup vs baseline: 4.4179x; 1.0161x over previous
//
#include <hip/hip_runtime.h>
#include <math.h>

typedef unsigned int  uint;
typedef unsigned short ushort;

#define N_NODES 50000
#define DIM     128
#define N_EDGES 800000
#define N_UID   4096
#define NB      8
#define LN_EPS  1e-5f
#define RST     132   // padded LDS row stride (floats)
#define CAP     1024  // staged CSR indices per block

// ---- bf16 helpers (storage only; all math fp32) ----
__device__ __forceinline__ float bf_lo(uint u) { return __builtin_bit_cast(float, u << 16); }
__device__ __forceinline__ float bf_hi(uint u) { return __builtin_bit_cast(float, u & 0xffff0000u); }
__device__ __forceinline__ uint pack_bf16(float a, float b) {   // RNE
    uint ua = __builtin_bit_cast(uint, a);
    uint ub = __builtin_bit_cast(uint, b);
    uint ra = (ua + 0x7fffu + ((ua >> 16) & 1u)) >> 16;
    uint rb = (ub + 0x7fffu + ((ub >> 16) & 1u)) >> 16;
    return ra | (rb << 16);
}

// ---------- CSR build ----------
__global__ __launch_bounds__(256) void deg_kernel(const int* __restrict__ dst, int* __restrict__ cnt) {
    int e = blockIdx.x * 256 + threadIdx.x;
    if (e < N_EDGES) atomicAdd(&cnt[dst[e]], 1);
}

__global__ __launch_bounds__(256) void scan1(const int* __restrict__ cnt, int* __restrict__ off,
                                             int* __restrict__ bsum) {
    __shared__ int sh[256];
    int t = threadIdx.x;
    int i = blockIdx.x * 256 + t;
    int v = (i < N_NODES) ? cnt[i] : 0;
    sh[t] = v;
    __syncthreads();
    for (int o = 1; o < 256; o <<= 1) {
        int x = (t >= o) ? sh[t - o] : 0;
        __syncthreads();
        sh[t] += x;
        __syncthreads();
    }
    if (i < N_NODES) off[i] = sh[t] - v;   // exclusive within block
    if (t == 255) bsum[blockIdx.x] = sh[255];
}

__global__ __launch_bounds__(256) void scan2(const int* __restrict__ bsum, int* __restrict__ bpre, int nblk) {
    __shared__ int sh[256];
    int t = threadIdx.x;
    int v = (t < nblk) ? bsum[t] : 0;
    sh[t] = v;
    __syncthreads();
    for (int o = 1; o < 256; o <<= 1) {
        int x = (t >= o) ? sh[t - o] : 0;
        __syncthreads();
        sh[t] += x;
        __syncthreads();
    }
    if (t < nblk) bpre[t] = sh[t] - v;     // exclusive
}

__global__ __launch_bounds__(256) void scan3(int* __restrict__ off, const int* __restrict__ bpre,
                                             int* __restrict__ cur) {
    int i = blockIdx.x * 256 + threadIdx.x;
    if (i < N_NODES) {
        int o = off[i] + bpre[blockIdx.x];
        off[i] = o;
        cur[i] = o;
    }
    if (i == 0) off[N_NODES] = N_EDGES;
}

__global__ __launch_bounds__(256) void fill_kernel(const int* __restrict__ src, const int* __restrict__ dst,
                                                   int* __restrict__ cur, int* __restrict__ csr) {
    int e = blockIdx.x * 256 + threadIdx.x;
    if (e < N_EDGES) {
        int p = atomicAdd(&cur[dst[e]], 1);
        csr[p] = src[e];
    }
}

// ---------- fp32 -> bf16 conversion of the embedding ----------
__global__ __launch_bounds__(256) void cvt_kernel(const float* __restrict__ in, ushort* __restrict__ out) {
    int i = blockIdx.x * 256 + threadIdx.x;          // one float4 / uint2 per thread
    if (i < N_NODES * DIM / 4) {
        const float4 v = ((const float4*)in)[i];
        uint2 p;
        p.x = pack_bf16(v.x, v.y);
        p.y = pack_bf16(v.z, v.w);
        ((uint2*)out)[i] = p;
    }
}

// ---------- fused layer: gather(bf16) + fp32 GEMM + LN + ELU ----------
// block = 256 threads, NB=8 node slots, one 32-lane stream per node.
// fin: bf16 rows (DIM elems, 256 B). OUT_BF16 ? fout=bf16 rows : fout=fp32 rows.
// uidmap!=nullptr: slot j handles node uidmap[base+j], writes row base+j.
template <bool OUT_BF16>
__global__ __launch_bounds__(256) void layer_kernel(
    const ushort* __restrict__ fin, void* __restrict__ fout,
    const int* __restrict__ off, const int* __restrict__ csr,
    const int* __restrict__ uidmap,
    const float* __restrict__ W, const float* __restrict__ bias,
    const float* __restrict__ gamma, const float* __restrict__ beta)
{
    __shared__ float xs[NB * RST];
    __shared__ float ivs[NB];
    __shared__ int   sidx[CAP];
    const int t    = threadIdx.x;
    const int base = blockIdx.x * NB;
    const int s    = t >> 5;          // stream / node slot 0..7
    const int lane = t & 31;          // uint2 index within 256B row (elems lane*4..+3)

    // ---- phase 0: node id, degree, CSR staging ----
    const int n  = uidmap ? uidmap[base + s] : (base + s);
    const int a0 = off[n], a1 = off[n + 1];
    if (lane == 0) ivs[s] = 1.0f / (float)(a1 - a0 + 1);

    int d0, d1, e0b = 0;
    bool fits = false;
    if (!uidmap) {
        e0b = off[base];
        const int cnt = off[base + NB] - e0b;
        fits = (cnt <= CAP);
        if (fits) {
            for (int i = t; i < cnt; i += 256) sidx[i] = csr[e0b + i];
        }
        d0 = a0 - e0b; d1 = a1 - e0b;
    } else {
        d0 = a0; d1 = a1;             // absolute indices into csr
    }

    // self row (bf16 -> fp32)
    float4 acc;
    {
        const uint2 sp = ((const uint2*)(fin + (size_t)n * DIM))[lane];
        acc.x = bf_lo(sp.x); acc.y = bf_hi(sp.x);
        acc.z = bf_lo(sp.y); acc.w = bf_hi(sp.y);
    }
    __syncthreads();                  // sidx visible

    // ---- phase 1: gather-aggregate, 16 rows in flight, masked tail round ----
    auto gath = [&](const int* __restrict__ idxp, float4 a) -> float4 {
        int e = d0;
        for (; e + 16 <= d1; e += 16) {
            int   id[16];
            uint2 v[16];
            #pragma unroll
            for (int k = 0; k < 16; ++k) id[k] = idxp[e + k];
            #pragma unroll
            for (int k = 0; k < 16; ++k)
                v[k] = ((const uint2*)(fin + (size_t)id[k] * DIM))[lane];
            #pragma unroll
            for (int k = 0; k < 16; ++k) {
                a.x += bf_lo(v[k].x); a.y += bf_hi(v[k].x);
                a.z += bf_lo(v[k].y); a.w += bf_hi(v[k].y);
            }
        }
        if (e < d1) {                 // one masked 16-wide round (clamped idx, 0/1 fma)
            const int last = d1 - 1;
            int   id[16];
            uint2 v[16];
            float m[16];
            #pragma unroll
            for (int k = 0; k < 16; ++k) {
                const int ee = e + k;
                id[k] = idxp[(ee <= last) ? ee : last];
                m[k]  = (ee <= last) ? 1.0f : 0.0f;
            }
            #pragma unroll
            for (int k = 0; k < 16; ++k)
                v[k] = ((const uint2*)(fin + (size_t)id[k] * DIM))[lane];
            #pragma unroll
            for (int k = 0; k < 16; ++k) {
                a.x = fmaf(m[k], bf_lo(v[k].x), a.x);
                a.y = fmaf(m[k], bf_hi(v[k].x), a.y);
                a.z = fmaf(m[k], bf_lo(v[k].y), a.z);
                a.w = fmaf(m[k], bf_hi(v[k].y), a.w);
            }
        }
        return a;
    };
    if (fits) acc = gath(sidx, acc);
    else      acc = gath(csr + e0b, acc);

    ((float4*)(xs + s * RST))[lane] = acc;   // raw sum (iv deferred to epilogue)
    __syncthreads();

    // ---- phase 2: GEMM y[j][c] = dot(W[c,:], x_raw[j,:]) (fp32) ----
    const int c = t & 127;
    const int h = t >> 7;                    // rows h*4 .. h*4+3
    float acc4[4];
    {
        #pragma unroll
        for (int j = 0; j < 4; ++j) acc4[j] = 0.0f;
        const float4* __restrict__ Wr = (const float4*)(W + (size_t)c * DIM);
        const float* xb = xs + h * 4 * RST;
        for (int k4 = 0; k4 < DIM / 4; ++k4) {
            const float4 w = Wr[k4];
            #pragma unroll
            for (int j = 0; j < 4; ++j) {
                const float4 xv = *((const float4*)(xb + j * RST + k4 * 4)); // broadcast
                acc4[j] = fmaf(w.x, xv.x, acc4[j]);
                acc4[j] = fmaf(w.y, xv.y, acc4[j]);
                acc4[j] = fmaf(w.z, xv.z, acc4[j]);
                acc4[j] = fmaf(w.w, xv.w, acc4[j]);
            }
        }
    }
    __syncthreads();                         // x reads done before overwrite
    {
        const float bv = bias[c];
        #pragma unroll
        for (int j = 0; j < 4; ++j)
            xs[(h * 4 + j) * RST + c] = acc4[j] * ivs[h * 4 + j] + bv;
    }
    __syncthreads();

    // ---- phase 3: LayerNorm + ELU; 32 threads per node, 4 dims each ----
    {
        const int j   = t >> 5;              // node slot 0..7
        const int seg = t & 31;              // 0..31
        const float4 v = *((const float4*)(xs + j * RST + seg * 4));
        float s1 = (v.x + v.y) + (v.z + v.w);
        float s2 = (v.x * v.x + v.y * v.y) + (v.z * v.z + v.w * v.w);
        #pragma unroll
        for (int m = 1; m < 32; m <<= 1) {
            s1 += __shfl_xor(s1, m);
            s2 += __shfl_xor(s2, m);
        }
        const float mu  = s1 * (1.0f / 128.0f);
        const float var = s2 * (1.0f / 128.0f) - mu * mu;
        const float rs  = rsqrtf(var + LN_EPS);
        const float4 g  = ((const float4*)gamma)[seg];
        const float4 bt = ((const float4*)beta)[seg];
        float4 o;
        float z;
        z = (v.x - mu) * rs * g.x + bt.x; o.x = (z > 0.0f) ? z : expm1f(z);
        z = (v.y - mu) * rs * g.y + bt.y; o.y = (z > 0.0f) ? z : expm1f(z);
        z = (v.z - mu) * rs * g.z + bt.z; o.z = (z > 0.0f) ? z : expm1f(z);
        z = (v.w - mu) * rs * g.w + bt.w; o.w = (z > 0.0f) ? z : expm1f(z);
        if (OUT_BF16) {
            uint2 p;
            p.x = pack_bf16(o.x, o.y);
            p.y = pack_bf16(o.z, o.w);
            ((uint2*)((ushort*)fout + (size_t)(base + j) * DIM))[seg] = p;
        } else {
            *((float4*)((float*)fout + (size_t)(base + j) * DIM + seg * 4)) = o;
        }
    }
}

extern "C" void kernel_launch(void* const* d_in, const int* in_sizes, int n_in,
                              void* d_out, int out_size, void* d_ws, size_t ws_size,
                              hipStream_t stream) {
    const float* emb   = (const float*)d_in[0];
    const float* W     = (const float*)d_in[1];
    const float* bias  = (const float*)d_in[2];
    const float* gamma = (const float*)d_in[3];
    const float* beta  = (const float*)d_in[4];
    const int*   src   = (const int*)d_in[5];
    const int*   dst   = (const int*)d_in[6];
    const int*   uid   = (const int*)d_in[7];

    // workspace layout (~42 MB)
    ushort* E    = (ushort*)d_ws;                    // 50000*128 bf16 (embedding)
    ushort* A    = E + (size_t)N_NODES * DIM;        // 50000*128 bf16
    ushort* B    = A + (size_t)N_NODES * DIM;        // 50000*128 bf16
    int*    cnt  = (int*)(B + (size_t)N_NODES * DIM);// 50000
    int*    off  = cnt + N_NODES;                    // 50001 (+pad)
    int*    cur  = off + (N_NODES + 4);              // 50000
    int*    bsum = cur + N_NODES;                    // 256
    int*    bpre = bsum + 256;                       // 256
    int*    csr  = bpre + 256;                       // 800000

    hipMemsetAsync(cnt, 0, N_NODES * sizeof(int), stream);

    const int eblk = (N_EDGES + 255) / 256;          // 3125
    const int nblk = (N_NODES + 255) / 256;          // 196
    deg_kernel<<<eblk, 256, 0, stream>>>(dst, cnt);
    scan1<<<nblk, 256, 0, stream>>>(cnt, off, bsum);
    scan2<<<1, 256, 0, stream>>>(bsum, bpre, nblk);
    scan3<<<nblk, 256, 0, stream>>>(off, bpre, cur);
    fill_kernel<<<eblk, 256, 0, stream>>>(src, dst, cur, csr);
    cvt_kernel<<<(N_NODES * DIM / 4 + 255) / 256, 256, 0, stream>>>(emb, E);

    const int lblocks = N_NODES / NB;                // 6250 exact
    layer_kernel<true><<<lblocks, 256, 0, stream>>>(E, A, off, csr, nullptr,
                                                    W, bias, gamma, beta);
    layer_kernel<true><<<lblocks, 256, 0, stream>>>(A, B, off, csr, nullptr,
                                                    W + DIM * DIM, bias + DIM, gamma + DIM, beta + DIM);
    // layer 3: only uid nodes are read — compute just those, fp32, straight into d_out
    layer_kernel<false><<<N_UID / NB, 256, 0, stream>>>(B, (float*)d_out, off, csr, uid,
                                                        W + 2 * DIM * DIM, bias + 2 * DIM,
                                                        gamma + 2 * DIM, beta + 2 * DIM);
}

// Round 6
// 406.627 us; speedup vs baseline: 4.6986x; 1.0635x over previous
//
#include <hip/hip_runtime.h>
#include <math.h>

typedef unsigned int   uint;
typedef unsigned short ushort;

#define N_NODES 50000
#define DIM     128
#define N_EDGES 800000
#define N_UID   4096
#define LN_EPS  1e-5f
#define RST     132   // padded LDS row stride (floats)
#define NB2     16    // nodes per gemm block

// ---- bf16 helpers (storage only; math fp32) ----
__device__ __forceinline__ float bf_lo(uint u) { return __builtin_bit_cast(float, u << 16); }
__device__ __forceinline__ float bf_hi(uint u) { return __builtin_bit_cast(float, u & 0xffff0000u); }
__device__ __forceinline__ uint pack_bf16(float a, float b) {   // RNE
    uint ua = __builtin_bit_cast(uint, a);
    uint ub = __builtin_bit_cast(uint, b);
    uint ra = (ua + 0x7fffu + ((ua >> 16) & 1u)) >> 16;
    uint rb = (ub + 0x7fffu + ((ub >> 16) & 1u)) >> 16;
    return ra | (rb << 16);
}

// ---------- CSR build ----------
__global__ __launch_bounds__(256) void deg_kernel(const int* __restrict__ dst, int* __restrict__ cnt) {
    int e = blockIdx.x * 256 + threadIdx.x;
    if (e < N_EDGES) atomicAdd(&cnt[dst[e]], 1);
}

__global__ __launch_bounds__(256) void scan1(const int* __restrict__ cnt, int* __restrict__ off,
                                             int* __restrict__ bsum) {
    __shared__ int sh[256];
    int t = threadIdx.x;
    int i = blockIdx.x * 256 + t;
    int v = (i < N_NODES) ? cnt[i] : 0;
    sh[t] = v;
    __syncthreads();
    for (int o = 1; o < 256; o <<= 1) {
        int x = (t >= o) ? sh[t - o] : 0;
        __syncthreads();
        sh[t] += x;
        __syncthreads();
    }
    if (i < N_NODES) off[i] = sh[t] - v;
    if (t == 255) bsum[blockIdx.x] = sh[255];
}

__global__ __launch_bounds__(256) void scan2(const int* __restrict__ bsum, int* __restrict__ bpre, int nblk) {
    __shared__ int sh[256];
    int t = threadIdx.x;
    int v = (t < nblk) ? bsum[t] : 0;
    sh[t] = v;
    __syncthreads();
    for (int o = 1; o < 256; o <<= 1) {
        int x = (t >= o) ? sh[t - o] : 0;
        __syncthreads();
        sh[t] += x;
        __syncthreads();
    }
    if (t < nblk) bpre[t] = sh[t] - v;
}

__global__ __launch_bounds__(256) void scan3(int* __restrict__ off, const int* __restrict__ bpre,
                                             int* __restrict__ cur) {
    int i = blockIdx.x * 256 + threadIdx.x;
    if (i < N_NODES) {
        int o = off[i] + bpre[blockIdx.x];
        off[i] = o;
        cur[i] = o;
    }
    if (i == 0) off[N_NODES] = N_EDGES;
}

__global__ __launch_bounds__(256) void fill_kernel(const int* __restrict__ src, const int* __restrict__ dst,
                                                   int* __restrict__ cur, int* __restrict__ csr) {
    int e = blockIdx.x * 256 + threadIdx.x;
    if (e < N_EDGES) {
        int p = atomicAdd(&cur[dst[e]], 1);
        csr[p] = src[e];
    }
}

// ---------- fp32 -> bf16 embedding convert ----------
__global__ __launch_bounds__(256) void cvt_kernel(const float* __restrict__ in, ushort* __restrict__ out) {
    int i = blockIdx.x * 256 + threadIdx.x;
    if (i < N_NODES * DIM / 4) {
        const float4 v = ((const float4*)in)[i];
        uint2 p;
        p.x = pack_bf16(v.x, v.y);
        p.y = pack_bf16(v.z, v.w);
        ((uint2*)out)[i] = p;
    }
}

// ---------- aggregate: x_mean[slot] = (self + sum_neigh) / (deg+1), bf16 ----------
// Barrier-free, LDS-free. One 32-lane stream per node slot; 16 rows in flight;
// next round's CSR indices prefetched into registers during the accumulate.
__global__ __launch_bounds__(256) void agg_kernel(
    const ushort* __restrict__ fin, ushort* __restrict__ xout,
    const int* __restrict__ off, const int* __restrict__ csr,
    const int* __restrict__ uidmap)
{
    const int t    = threadIdx.x;
    const int s    = t >> 5;
    const int lane = t & 31;                     // uint2 index within 256B row
    const int slot = blockIdx.x * 8 + s;
    const int n    = uidmap ? uidmap[slot] : slot;
    const int d0   = off[n], d1 = off[n + 1];
    const int deg  = d1 - d0;

    float4 acc;
    {
        const uint2 sp = ((const uint2*)(fin + (size_t)n * DIM))[lane];
        acc.x = bf_lo(sp.x); acc.y = bf_hi(sp.x);
        acc.z = bf_lo(sp.y); acc.w = bf_hi(sp.y);
    }

    const int nfull = deg >> 4;
    int e = d0;
    int id[16];
    if (nfull > 0) {
        #pragma unroll
        for (int k = 0; k < 16; ++k) id[k] = csr[e + k];
    }
    for (int r = 0; r < nfull; ++r) {
        uint2 v[16];
        #pragma unroll
        for (int k = 0; k < 16; ++k)
            v[k] = ((const uint2*)(fin + (size_t)id[k] * DIM))[lane];
        int idn[16];
        if (r + 1 < nfull) {                     // prefetch next round's indices
            #pragma unroll
            for (int k = 0; k < 16; ++k) idn[k] = csr[e + 16 + k];
        }
        #pragma unroll
        for (int k = 0; k < 16; ++k) {
            acc.x += bf_lo(v[k].x); acc.y += bf_hi(v[k].x);
            acc.z += bf_lo(v[k].y); acc.w += bf_hi(v[k].y);
        }
        if (r + 1 < nfull) {
            #pragma unroll
            for (int k = 0; k < 16; ++k) id[k] = idn[k];
        }
        e += 16;
    }
    if (e < d1) {                                // one masked 16-wide tail round
        const int last = d1 - 1;
        int   idt[16];
        float m[16];
        #pragma unroll
        for (int k = 0; k < 16; ++k) {
            const int ee = e + k;
            idt[k] = csr[(ee <= last) ? ee : last];
            m[k]   = (ee <= last) ? 1.0f : 0.0f;
        }
        uint2 v[16];
        #pragma unroll
        for (int k = 0; k < 16; ++k)
            v[k] = ((const uint2*)(fin + (size_t)idt[k] * DIM))[lane];
        #pragma unroll
        for (int k = 0; k < 16; ++k) {
            acc.x = fmaf(m[k], bf_lo(v[k].x), acc.x);
            acc.y = fmaf(m[k], bf_hi(v[k].x), acc.y);
            acc.z = fmaf(m[k], bf_lo(v[k].y), acc.z);
            acc.w = fmaf(m[k], bf_hi(v[k].y), acc.w);
        }
    }

    const float iv = 1.0f / (float)(deg + 1);
    uint2 p;
    p.x = pack_bf16(acc.x * iv, acc.y * iv);
    p.y = pack_bf16(acc.z * iv, acc.w * iv);
    ((uint2*)(xout + (size_t)slot * DIM))[lane] = p;
}

// ---------- dense: y = x_mean @ W^T + b, LN, ELU ----------
// block = 256 threads, NB2=16 rows. rows = compact [base .. base+16).
template <bool OUT_BF16>
__global__ __launch_bounds__(256) void gemm_kernel(
    const ushort* __restrict__ xin, void* __restrict__ fout,
    const float* __restrict__ W, const float* __restrict__ bias,
    const float* __restrict__ gamma, const float* __restrict__ beta)
{
    __shared__ float xs[NB2 * RST];
    const int t    = threadIdx.x;
    const int base = blockIdx.x * NB2;

    // ---- load 16 rows bf16 -> fp32 LDS; thread (r = t>>4, seg = t&15) ----
    {
        const int r = t >> 4, seg = t & 15;
        const uint4 q = ((const uint4*)(xin + (size_t)(base + r) * DIM))[seg];
        float* dp = xs + r * RST + seg * 8;
        dp[0] = bf_lo(q.x); dp[1] = bf_hi(q.x);
        dp[2] = bf_lo(q.y); dp[3] = bf_hi(q.y);
        dp[4] = bf_lo(q.z); dp[5] = bf_hi(q.z);
        dp[6] = bf_lo(q.w); dp[7] = bf_hi(q.w);
    }
    __syncthreads();

    // ---- GEMM: thread (c = t&127, h = t>>7) does 8 rows ----
    const int c = t & 127;
    const int h = t >> 7;
    float acc[8];
    {
        #pragma unroll
        for (int j = 0; j < 8; ++j) acc[j] = 0.0f;
        const float4* __restrict__ Wr = (const float4*)(W + (size_t)c * DIM);
        const float* xb = xs + h * 8 * RST;
        for (int k4 = 0; k4 < DIM / 4; ++k4) {
            const float4 w = Wr[k4];
            #pragma unroll
            for (int j = 0; j < 8; ++j) {
                const float4 xv = *((const float4*)(xb + j * RST + k4 * 4)); // broadcast
                acc[j] = fmaf(w.x, xv.x, acc[j]);
                acc[j] = fmaf(w.y, xv.y, acc[j]);
                acc[j] = fmaf(w.z, xv.z, acc[j]);
                acc[j] = fmaf(w.w, xv.w, acc[j]);
            }
        }
    }
    __syncthreads();
    {
        const float bv = bias[c];
        #pragma unroll
        for (int j = 0; j < 8; ++j)
            xs[(h * 8 + j) * RST + c] = acc[j] + bv;
    }
    __syncthreads();

    // ---- LN + ELU: thread (node j = t>>4, seg = t&15), 8 dims each ----
    {
        const int j   = t >> 4;
        const int seg = t & 15;
        const float* yr = xs + j * RST + seg * 8;
        const float4 a0 = ((const float4*)yr)[0];
        const float4 a1 = ((const float4*)yr)[1];
        float vs[8] = {a0.x, a0.y, a0.z, a0.w, a1.x, a1.y, a1.z, a1.w};
        float s1 = 0.0f, s2 = 0.0f;
        #pragma unroll
        for (int i = 0; i < 8; ++i) { s1 += vs[i]; s2 += vs[i] * vs[i]; }
        #pragma unroll
        for (int m = 1; m < 16; m <<= 1) {
            s1 += __shfl_xor(s1, m);
            s2 += __shfl_xor(s2, m);
        }
        const float mu  = s1 * (1.0f / 128.0f);
        const float var = s2 * (1.0f / 128.0f) - mu * mu;
        const float rs  = rsqrtf(var + LN_EPS);
        const int db = seg * 8;
        float ov[8];
        #pragma unroll
        for (int i = 0; i < 8; ++i) {
            const float z = (vs[i] - mu) * rs * gamma[db + i] + beta[db + i];
            ov[i] = (z > 0.0f) ? z : expm1f(z);
        }
        if (OUT_BF16) {
            uint2 p;
            p.x = pack_bf16(ov[0], ov[1]);
            p.y = pack_bf16(ov[2], ov[3]);
            uint2 q;
            q.x = pack_bf16(ov[4], ov[5]);
            q.y = pack_bf16(ov[6], ov[7]);
            uint2* op = (uint2*)((ushort*)fout + (size_t)(base + j) * DIM + db);
            op[0] = p;
            op[1] = q;
        } else {
            float4* op = (float4*)((float*)fout + (size_t)(base + j) * DIM + db);
            op[0] = make_float4(ov[0], ov[1], ov[2], ov[3]);
            op[1] = make_float4(ov[4], ov[5], ov[6], ov[7]);
        }
    }
}

extern "C" void kernel_launch(void* const* d_in, const int* in_sizes, int n_in,
                              void* d_out, int out_size, void* d_ws, size_t ws_size,
                              hipStream_t stream) {
    const float* emb   = (const float*)d_in[0];
    const float* W     = (const float*)d_in[1];
    const float* bias  = (const float*)d_in[2];
    const float* gamma = (const float*)d_in[3];
    const float* beta  = (const float*)d_in[4];
    const int*   src   = (const int*)d_in[5];
    const int*   dst   = (const int*)d_in[6];
    const int*   uid   = (const int*)d_in[7];

    // workspace layout (~55 MB)
    ushort* E    = (ushort*)d_ws;                    // 50000*128 bf16 (embedding)
    ushort* X    = E + (size_t)N_NODES * DIM;        // 50000*128 bf16 (x_mean)
    ushort* A    = X + (size_t)N_NODES * DIM;        // 50000*128 bf16 (feats L1)
    ushort* B    = A + (size_t)N_NODES * DIM;        // 50000*128 bf16 (feats L2)
    int*    cnt  = (int*)(B + (size_t)N_NODES * DIM);// 50000
    int*    off  = cnt + N_NODES;                    // 50001 (+pad)
    int*    cur  = off + (N_NODES + 4);              // 50000
    int*    bsum = cur + N_NODES;                    // 256
    int*    bpre = bsum + 256;                       // 256
    int*    csr  = bpre + 256;                       // 800000

    hipMemsetAsync(cnt, 0, N_NODES * sizeof(int), stream);

    const int eblk = (N_EDGES + 255) / 256;          // 3125
    const int nblk = (N_NODES + 255) / 256;          // 196
    deg_kernel<<<eblk, 256, 0, stream>>>(dst, cnt);
    scan1<<<nblk, 256, 0, stream>>>(cnt, off, bsum);
    scan2<<<1, 256, 0, stream>>>(bsum, bpre, nblk);
    scan3<<<nblk, 256, 0, stream>>>(off, bpre, cur);
    fill_kernel<<<eblk, 256, 0, stream>>>(src, dst, cur, csr);
    cvt_kernel<<<(N_NODES * DIM / 4 + 255) / 256, 256, 0, stream>>>(emb, E);

    // layer 1
    agg_kernel<<<N_NODES / 8, 256, 0, stream>>>(E, X, off, csr, nullptr);
    gemm_kernel<true><<<N_NODES / NB2, 256, 0, stream>>>(X, A, W, bias, gamma, beta);
    // layer 2
    agg_kernel<<<N_NODES / 8, 256, 0, stream>>>(A, X, off, csr, nullptr);
    gemm_kernel<true><<<N_NODES / NB2, 256, 0, stream>>>(X, B, W + DIM * DIM, bias + DIM,
                                                         gamma + DIM, beta + DIM);
    // layer 3: only the uid nodes are ever read — aggregate + transform just those
    agg_kernel<<<N_UID / 8, 256, 0, stream>>>(B, X, off, csr, uid);
    gemm_kernel<false><<<N_UID / NB2, 256, 0, stream>>>(X, (float*)d_out, W + 2 * DIM * DIM,
                                                        bias + 2 * DIM, gamma + 2 * DIM, beta + 2 * DIM);
}

// Round 7
// 302.994 us; speedup vs baseline: 6.3057x; 1.3420x over previous
//
#include <hip/hip_runtime.h>
#include <math.h>

typedef unsigned int   uint;
typedef unsigned short ushort;

#define N_NODES 50000
#define DIM     128
#define N_EDGES 800000
#define N_UID   4096
#define LN_EPS  1e-5f
#define RST     132   // padded LDS row stride (floats)

typedef __attribute__((ext_vector_type(8))) short bf16x8;
typedef __attribute__((ext_vector_type(4))) float f32x4;
typedef __attribute__((ext_vector_type(4))) uint  u32x4;

// ---- bf16 helpers (storage only; math fp32) ----
__device__ __forceinline__ float bf_lo(uint u) { return __builtin_bit_cast(float, u << 16); }
__device__ __forceinline__ float bf_hi(uint u) { return __builtin_bit_cast(float, u & 0xffff0000u); }
__device__ __forceinline__ uint pack_bf16(float a, float b) {   // RNE
    uint ua = __builtin_bit_cast(uint, a);
    uint ub = __builtin_bit_cast(uint, b);
    uint ra = (ua + 0x7fffu + ((ua >> 16) & 1u)) >> 16;
    uint rb = (ub + 0x7fffu + ((ub >> 16) & 1u)) >> 16;
    return ra | (rb << 16);
}
__device__ __forceinline__ ushort bfr1(float f) {
    uint u = __builtin_bit_cast(uint, f);
    return (ushort)((u + 0x7fffu + ((u >> 16) & 1u)) >> 16);
}

// ---------- CSR build ----------
__global__ __launch_bounds__(256) void deg_kernel(const int* __restrict__ dst, int* __restrict__ cnt) {
    int e = blockIdx.x * 256 + threadIdx.x;
    if (e < N_EDGES) atomicAdd(&cnt[dst[e]], 1);
}

__global__ __launch_bounds__(256) void scan1(const int* __restrict__ cnt, int* __restrict__ off,
                                             int* __restrict__ bsum) {
    __shared__ int sh[256];
    int t = threadIdx.x;
    int i = blockIdx.x * 256 + t;
    int v = (i < N_NODES) ? cnt[i] : 0;
    sh[t] = v;
    __syncthreads();
    for (int o = 1; o < 256; o <<= 1) {
        int x = (t >= o) ? sh[t - o] : 0;
        __syncthreads();
        sh[t] += x;
        __syncthreads();
    }
    if (i < N_NODES) off[i] = sh[t] - v;
    if (t == 255) bsum[blockIdx.x] = sh[255];
}

__global__ __launch_bounds__(256) void scan2(const int* __restrict__ bsum, int* __restrict__ bpre, int nblk) {
    __shared__ int sh[256];
    int t = threadIdx.x;
    int v = (t < nblk) ? bsum[t] : 0;
    sh[t] = v;
    __syncthreads();
    for (int o = 1; o < 256; o <<= 1) {
        int x = (t >= o) ? sh[t - o] : 0;
        __syncthreads();
        sh[t] += x;
        __syncthreads();
    }
    if (t < nblk) bpre[t] = sh[t] - v;
}

__global__ __launch_bounds__(256) void scan3(int* __restrict__ off, const int* __restrict__ bpre,
                                             int* __restrict__ cur) {
    int i = blockIdx.x * 256 + threadIdx.x;
    if (i < N_NODES) {
        int o = off[i] + bpre[blockIdx.x];
        off[i] = o;
        cur[i] = o;
    }
    if (i == 0) off[N_NODES] = N_EDGES;
}

__global__ __launch_bounds__(256) void fill_kernel(const int* __restrict__ src, const int* __restrict__ dst,
                                                   int* __restrict__ cur, int* __restrict__ csr) {
    int e = blockIdx.x * 256 + threadIdx.x;
    if (e < N_EDGES) {
        int p = atomicAdd(&cur[dst[e]], 1);
        csr[p] = src[e];
    }
}

// ---------- fp32 -> bf16 converts ----------
__global__ __launch_bounds__(256) void cvt_kernel(const float* __restrict__ in, ushort* __restrict__ out) {
    int i = blockIdx.x * 256 + threadIdx.x;
    if (i < N_NODES * DIM / 4) {
        const float4 v = ((const float4*)in)[i];
        uint2 p;
        p.x = pack_bf16(v.x, v.y);
        p.y = pack_bf16(v.z, v.w);
        ((uint2*)out)[i] = p;
    }
}

__global__ __launch_bounds__(256) void wcvt_kernel(const float* __restrict__ in, ushort* __restrict__ out) {
    int i = blockIdx.x * 256 + threadIdx.x;
    if (i < 3 * DIM * DIM) out[i] = bfr1(in[i]);
}

// ---------- aggregate: x_mean[slot] = (self + sum_neigh) / (deg+1), bf16 ----------
// Barrier-free, LDS-free. One 32-lane stream per node slot; 16 rows in flight.
__global__ __launch_bounds__(256) void agg_kernel(
    const ushort* __restrict__ fin, ushort* __restrict__ xout,
    const int* __restrict__ off, const int* __restrict__ csr,
    const int* __restrict__ uidmap)
{
    const int t    = threadIdx.x;
    const int s    = t >> 5;
    const int lane = t & 31;                     // uint2 index within 256B row
    const int slot = blockIdx.x * 8 + s;
    const int n    = uidmap ? uidmap[slot] : slot;
    const int d0   = off[n], d1 = off[n + 1];
    const int deg  = d1 - d0;

    float4 acc;
    {
        const uint2 sp = ((const uint2*)(fin + (size_t)n * DIM))[lane];
        acc.x = bf_lo(sp.x); acc.y = bf_hi(sp.x);
        acc.z = bf_lo(sp.y); acc.w = bf_hi(sp.y);
    }

    const int nfull = deg >> 4;
    int e = d0;
    int id[16];
    if (nfull > 0) {
        #pragma unroll
        for (int k = 0; k < 16; ++k) id[k] = csr[e + k];
    }
    for (int r = 0; r < nfull; ++r) {
        uint2 v[16];
        #pragma unroll
        for (int k = 0; k < 16; ++k)
            v[k] = ((const uint2*)(fin + (size_t)id[k] * DIM))[lane];
        int idn[16];
        if (r + 1 < nfull) {
            #pragma unroll
            for (int k = 0; k < 16; ++k) idn[k] = csr[e + 16 + k];
        }
        #pragma unroll
        for (int k = 0; k < 16; ++k) {
            acc.x += bf_lo(v[k].x); acc.y += bf_hi(v[k].x);
            acc.z += bf_lo(v[k].y); acc.w += bf_hi(v[k].y);
        }
        if (r + 1 < nfull) {
            #pragma unroll
            for (int k = 0; k < 16; ++k) id[k] = idn[k];
        }
        e += 16;
    }
    if (e < d1) {                                // one masked 16-wide tail round
        const int last = d1 - 1;
        int   idt[16];
        float m[16];
        #pragma unroll
        for (int k = 0; k < 16; ++k) {
            const int ee = e + k;
            idt[k] = csr[(ee <= last) ? ee : last];
            m[k]   = (ee <= last) ? 1.0f : 0.0f;
        }
        uint2 v[16];
        #pragma unroll
        for (int k = 0; k < 16; ++k)
            v[k] = ((const uint2*)(fin + (size_t)idt[k] * DIM))[lane];
        #pragma unroll
        for (int k = 0; k < 16; ++k) {
            acc.x = fmaf(m[k], bf_lo(v[k].x), acc.x);
            acc.y = fmaf(m[k], bf_hi(v[k].x), acc.y);
            acc.z = fmaf(m[k], bf_lo(v[k].y), acc.z);
            acc.w = fmaf(m[k], bf_hi(v[k].y), acc.w);
        }
    }

    const float iv = 1.0f / (float)(deg + 1);
    uint2 p;
    p.x = pack_bf16(acc.x * iv, acc.y * iv);
    p.y = pack_bf16(acc.z * iv, acc.w * iv);
    ((uint2*)(xout + (size_t)slot * DIM))[lane] = p;
}

// ---------- MFMA dense: y = x_mean @ W^T (+b), LN, ELU ----------
// block = 256 threads (4 waves), 32 rows × 128 cols of output.
// wave w: rows (w>>1)*16, cols (w&1)*64 (4 col-tiles of 16).
// A-frag: lane reads x[row + (lane&15)][kk*32 + (lane>>4)*8 ..+7]  (16B)
// B-frag: lane reads wb[col + (lane&15)][kk*32 + (lane>>4)*8 ..+7] (16B)
// C/D: col = lane&15, row = (lane>>4)*4 + reg   [measured m89]
template <bool OUT_BF16>
__global__ __launch_bounds__(256) void mgemm_kernel(
    const ushort* __restrict__ xin, void* __restrict__ fout,
    const ushort* __restrict__ wb, const float* __restrict__ bias,
    const float* __restrict__ gamma, const float* __restrict__ beta, int nrows)
{
    __shared__ float ys[32 * RST];
    const int t    = threadIdx.x;
    const int wave = t >> 6, lane = t & 63;
    const int rows = blockIdx.x * 32;
    const int row_off = (wave >> 1) * 16;
    const int col_off = (wave & 1) * 64;
    const int lm   = lane & 15;
    const int quad = lane >> 4;

    f32x4 acc[4] = {f32x4{0,0,0,0}, f32x4{0,0,0,0}, f32x4{0,0,0,0}, f32x4{0,0,0,0}};
    const ushort* __restrict__ xrow = xin + (size_t)(rows + row_off + lm) * DIM + quad * 8;
    const ushort* __restrict__ wrow = wb  + (size_t)(col_off + lm) * DIM + quad * 8;
    #pragma unroll
    for (int kk = 0; kk < 4; ++kk) {
        const bf16x8 a = __builtin_bit_cast(bf16x8, *(const u32x4*)(xrow + kk * 32));
        #pragma unroll
        for (int c = 0; c < 4; ++c) {
            const bf16x8 b = __builtin_bit_cast(bf16x8,
                *(const u32x4*)(wrow + (size_t)c * 16 * DIM + kk * 32));
            acc[c] = __builtin_amdgcn_mfma_f32_16x16x32_bf16(a, b, acc[c], 0, 0, 0);
        }
    }

    // dump accumulators to LDS (row-major, padded stride)
    #pragma unroll
    for (int c = 0; c < 4; ++c) {
        #pragma unroll
        for (int r = 0; r < 4; ++r)
            ys[(row_off + quad * 4 + r) * RST + col_off + c * 16 + lm] = acc[c][r];
    }
    __syncthreads();

    // LN + ELU: 8 threads per row, 16 dims each
    {
        const int r   = t >> 3;              // row 0..31
        const int seg = t & 7;               // 0..7
        const int db  = seg * 16;
        const float* yr = ys + r * RST + db;
        float vs[16];
        #pragma unroll
        for (int q = 0; q < 4; ++q) {
            const float4 y4 = ((const float4*)yr)[q];
            const float4 b4 = ((const float4*)(bias + db))[q];
            vs[q * 4 + 0] = y4.x + b4.x;
            vs[q * 4 + 1] = y4.y + b4.y;
            vs[q * 4 + 2] = y4.z + b4.z;
            vs[q * 4 + 3] = y4.w + b4.w;
        }
        float s1 = 0.0f, s2 = 0.0f;
        #pragma unroll
        for (int i = 0; i < 16; ++i) { s1 += vs[i]; s2 += vs[i] * vs[i]; }
        #pragma unroll
        for (int m = 1; m < 8; m <<= 1) {
            s1 += __shfl_xor(s1, m);
            s2 += __shfl_xor(s2, m);
        }
        const float mu  = s1 * (1.0f / 128.0f);
        const float var = s2 * (1.0f / 128.0f) - mu * mu;
        const float rs  = rsqrtf(var + LN_EPS);
        float ov[16];
        #pragma unroll
        for (int q = 0; q < 4; ++q) {
            const float4 g4 = ((const float4*)(gamma + db))[q];
            const float4 t4 = ((const float4*)(beta + db))[q];
            float z;
            z = (vs[q*4+0] - mu) * rs * g4.x + t4.x; ov[q*4+0] = (z > 0.0f) ? z : expm1f(z);
            z = (vs[q*4+1] - mu) * rs * g4.y + t4.y; ov[q*4+1] = (z > 0.0f) ? z : expm1f(z);
            z = (vs[q*4+2] - mu) * rs * g4.z + t4.z; ov[q*4+2] = (z > 0.0f) ? z : expm1f(z);
            z = (vs[q*4+3] - mu) * rs * g4.w + t4.w; ov[q*4+3] = (z > 0.0f) ? z : expm1f(z);
        }
        const int n = rows + r;
        if (n < nrows) {
            if (OUT_BF16) {
                uint4 p0, p1;
                p0.x = pack_bf16(ov[0],  ov[1]);  p0.y = pack_bf16(ov[2],  ov[3]);
                p0.z = pack_bf16(ov[4],  ov[5]);  p0.w = pack_bf16(ov[6],  ov[7]);
                p1.x = pack_bf16(ov[8],  ov[9]);  p1.y = pack_bf16(ov[10], ov[11]);
                p1.z = pack_bf16(ov[12], ov[13]); p1.w = pack_bf16(ov[14], ov[15]);
                uint4* op = (uint4*)((ushort*)fout + (size_t)n * DIM + db);
                op[0] = p0;    // note: db is a multiple of 16 elems = 32B, uint4 = 16B: two stores
                op[1] = p1;
            } else {
                float* op = (float*)fout + (size_t)n * DIM + db;
                ((float4*)op)[0] = make_float4(ov[0],  ov[1],  ov[2],  ov[3]);
                ((float4*)op)[1] = make_float4(ov[4],  ov[5],  ov[6],  ov[7]);
                ((float4*)op)[2] = make_float4(ov[8],  ov[9],  ov[10], ov[11]);
                ((float4*)op)[3] = make_float4(ov[12], ov[13], ov[14], ov[15]);
            }
        }
    }
}

extern "C" void kernel_launch(void* const* d_in, const int* in_sizes, int n_in,
                              void* d_out, int out_size, void* d_ws, size_t ws_size,
                              hipStream_t stream) {
    const float* emb   = (const float*)d_in[0];
    const float* W     = (const float*)d_in[1];
    const float* bias  = (const float*)d_in[2];
    const float* gamma = (const float*)d_in[3];
    const float* beta  = (const float*)d_in[4];
    const int*   src   = (const int*)d_in[5];
    const int*   dst   = (const int*)d_in[6];
    const int*   uid   = (const int*)d_in[7];

    // workspace layout (~55 MB)
    ushort* E    = (ushort*)d_ws;                     // 50000*128 bf16 (embedding)
    ushort* X    = E + (size_t)N_NODES * DIM;         // (50000+32)*128 bf16 (x_mean, padded)
    ushort* A    = X + (size_t)(N_NODES + 32) * DIM;  // 50000*128 bf16
    ushort* B    = A + (size_t)N_NODES * DIM;         // 50000*128 bf16
    ushort* WB   = B + (size_t)N_NODES * DIM;         // 3*128*128 bf16
    int*    cnt  = (int*)(WB + 3 * DIM * DIM);        // 50000
    int*    off  = cnt + N_NODES;                     // 50001 (+pad)
    int*    cur  = off + (N_NODES + 4);               // 50000
    int*    bsum = cur + N_NODES;                     // 256
    int*    bpre = bsum + 256;                        // 256
    int*    csr  = bpre + 256;                        // 800000

    hipMemsetAsync(cnt, 0, N_NODES * sizeof(int), stream);

    const int eblk = (N_EDGES + 255) / 256;           // 3125
    const int nblk = (N_NODES + 255) / 256;           // 196
    deg_kernel<<<eblk, 256, 0, stream>>>(dst, cnt);
    scan1<<<nblk, 256, 0, stream>>>(cnt, off, bsum);
    scan2<<<1, 256, 0, stream>>>(bsum, bpre, nblk);
    scan3<<<nblk, 256, 0, stream>>>(off, bpre, cur);
    fill_kernel<<<eblk, 256, 0, stream>>>(src, dst, cur, csr);
    cvt_kernel<<<(N_NODES * DIM / 4 + 255) / 256, 256, 0, stream>>>(emb, E);
    wcvt_kernel<<<(3 * DIM * DIM + 255) / 256, 256, 0, stream>>>(W, WB);

    const int gfull = (N_NODES + 31) / 32;            // 1563
    // layer 1
    agg_kernel<<<N_NODES / 8, 256, 0, stream>>>(E, X, off, csr, nullptr);
    mgemm_kernel<true><<<gfull, 256, 0, stream>>>(X, A, WB, bias, gamma, beta, N_NODES);
    // layer 2
    agg_kernel<<<N_NODES / 8, 256, 0, stream>>>(A, X, off, csr, nullptr);
    mgemm_kernel<true><<<gfull, 256, 0, stream>>>(X, B, WB + DIM * DIM, bias + DIM,
                                                  gamma + DIM, beta + DIM, N_NODES);
    // layer 3: only uid nodes are read — aggregate + transform just those
    agg_kernel<<<N_UID / 8, 256, 0, stream>>>(B, X, off, csr, uid);
    mgemm_kernel<false><<<N_UID / 32, 256, 0, stream>>>(X, (float*)d_out, WB + 2 * DIM * DIM,
                                                        bias + 2 * DIM, gamma + 2 * DIM,
                                                        beta + 2 * DIM, N_UID);
}

// Round 8
// 302.355 us; speedup vs baseline: 6.3190x; 1.0021x over previous
//
#include <hip/hip_runtime.h>
#include <math.h>

typedef unsigned int   uint;
typedef unsigned short ushort;

#define N_NODES 50000
#define DIM     128
#define N_EDGES 800000
#define N_UID   4096
#define LN_EPS  1e-5f
#define RST     132   // padded LDS row stride (floats)

typedef __attribute__((ext_vector_type(8))) short bf16x8;
typedef __attribute__((ext_vector_type(4))) float f32x4;
typedef __attribute__((ext_vector_type(4))) uint  u32x4;

// ---- bf16 helpers (storage only; math fp32) ----
__device__ __forceinline__ float bf_lo(uint u) { return __builtin_bit_cast(float, u << 16); }
__device__ __forceinline__ float bf_hi(uint u) { return __builtin_bit_cast(float, u & 0xffff0000u); }
__device__ __forceinline__ uint pack_bf16(float a, float b) {   // RNE
    uint ua = __builtin_bit_cast(uint, a);
    uint ub = __builtin_bit_cast(uint, b);
    uint ra = (ua + 0x7fffu + ((ua >> 16) & 1u)) >> 16;
    uint rb = (ub + 0x7fffu + ((ub >> 16) & 1u)) >> 16;
    return ra | (rb << 16);
}
__device__ __forceinline__ ushort bfr1(float f) {
    uint u = __builtin_bit_cast(uint, f);
    return (ushort)((u + 0x7fffu + ((u >> 16) & 1u)) >> 16);
}

// ---------- CSR build ----------
// 4 edges per thread: independent atomics pipeline the ~300-cyc atomic latency.
__global__ __launch_bounds__(256) void deg_kernel(const int* __restrict__ dst, int* __restrict__ cnt) {
    int i = blockIdx.x * 256 + threadIdx.x;          // int4 index
    if (i < N_EDGES / 4) {
        const int4 d = ((const int4*)dst)[i];
        atomicAdd(&cnt[d.x], 1);
        atomicAdd(&cnt[d.y], 1);
        atomicAdd(&cnt[d.z], 1);
        atomicAdd(&cnt[d.w], 1);
    }
}

__global__ __launch_bounds__(256) void scan1(const int* __restrict__ cnt, int* __restrict__ off,
                                             int* __restrict__ bsum) {
    __shared__ int sh[256];
    int t = threadIdx.x;
    int i = blockIdx.x * 256 + t;
    int v = (i < N_NODES) ? cnt[i] : 0;
    sh[t] = v;
    __syncthreads();
    for (int o = 1; o < 256; o <<= 1) {
        int x = (t >= o) ? sh[t - o] : 0;
        __syncthreads();
        sh[t] += x;
        __syncthreads();
    }
    if (i < N_NODES) off[i] = sh[t] - v;
    if (t == 255) bsum[blockIdx.x] = sh[255];
}

__global__ __launch_bounds__(256) void scan2(const int* __restrict__ bsum, int* __restrict__ bpre, int nblk) {
    __shared__ int sh[256];
    int t = threadIdx.x;
    int v = (t < nblk) ? bsum[t] : 0;
    sh[t] = v;
    __syncthreads();
    for (int o = 1; o < 256; o <<= 1) {
        int x = (t >= o) ? sh[t - o] : 0;
        __syncthreads();
        sh[t] += x;
        __syncthreads();
    }
    if (t < nblk) bpre[t] = sh[t] - v;
}

__global__ __launch_bounds__(256) void scan3(int* __restrict__ off, const int* __restrict__ bpre,
                                             int* __restrict__ cur) {
    int i = blockIdx.x * 256 + threadIdx.x;
    if (i < N_NODES) {
        int o = off[i] + bpre[blockIdx.x];
        off[i] = o;
        cur[i] = o;
    }
    if (i == 0) off[N_NODES] = N_EDGES;
}

__global__ __launch_bounds__(256) void fill_kernel(const int* __restrict__ src, const int* __restrict__ dst,
                                                   int* __restrict__ cur, int* __restrict__ csr) {
    int i = blockIdx.x * 256 + threadIdx.x;          // int4 index
    if (i < N_EDGES / 4) {
        const int4 s = ((const int4*)src)[i];
        const int4 d = ((const int4*)dst)[i];
        const int p0 = atomicAdd(&cur[d.x], 1);
        const int p1 = atomicAdd(&cur[d.y], 1);
        const int p2 = atomicAdd(&cur[d.z], 1);
        const int p3 = atomicAdd(&cur[d.w], 1);
        csr[p0] = s.x;
        csr[p1] = s.y;
        csr[p2] = s.z;
        csr[p3] = s.w;
    }
}

// ---------- fp32 -> bf16 converts ----------
__global__ __launch_bounds__(256) void cvt_kernel(const float* __restrict__ in, ushort* __restrict__ out) {
    int i = blockIdx.x * 256 + threadIdx.x;
    if (i < N_NODES * DIM / 4) {
        const float4 v = ((const float4*)in)[i];
        uint2 p;
        p.x = pack_bf16(v.x, v.y);
        p.y = pack_bf16(v.z, v.w);
        ((uint2*)out)[i] = p;
    }
}

__global__ __launch_bounds__(256) void wcvt_kernel(const float* __restrict__ in, ushort* __restrict__ out) {
    int i = blockIdx.x * 256 + threadIdx.x;
    if (i < 3 * DIM * DIM) out[i] = bfr1(in[i]);
}

// ---------- aggregate: x_mean[slot] = (self + sum_neigh) / (deg+1), bf16 ----------
// Barrier-free, LDS-free. 16-lane stream per node (uint4 = 16B per lane covers a
// 256B row with 16 lanes), 4 nodes per wave, 16 nodes per block, 8 rows in flight.
__global__ __launch_bounds__(256) void agg_kernel(
    const ushort* __restrict__ fin, ushort* __restrict__ xout,
    const int* __restrict__ off, const int* __restrict__ csr,
    const int* __restrict__ uidmap)
{
    const int t    = threadIdx.x;
    const int lx   = t & 15;                     // uint4 index within 256B row
    const int slot = blockIdx.x * 16 + (t >> 4); // node slot (16 per block)
    const int n    = uidmap ? uidmap[slot] : slot;
    const int d0   = off[n], d1 = off[n + 1];
    const int deg  = d1 - d0;

    float2 A0, A1, A2, A3;
    {
        const uint4 sp = ((const uint4*)(fin + (size_t)n * DIM))[lx];
        A0 = make_float2(bf_lo(sp.x), bf_hi(sp.x));
        A1 = make_float2(bf_lo(sp.y), bf_hi(sp.y));
        A2 = make_float2(bf_lo(sp.z), bf_hi(sp.z));
        A3 = make_float2(bf_lo(sp.w), bf_hi(sp.w));
    }

    const int nfull = deg >> 3;
    int e = d0;
    int id[8];
    if (nfull > 0) {
        #pragma unroll
        for (int k = 0; k < 8; ++k) id[k] = csr[e + k];
    }
    for (int r = 0; r < nfull; ++r) {
        uint4 v[8];
        #pragma unroll
        for (int k = 0; k < 8; ++k)
            v[k] = ((const uint4*)(fin + (size_t)id[k] * DIM))[lx];
        int idn[8];
        if (r + 1 < nfull) {                     // prefetch next round's indices
            #pragma unroll
            for (int k = 0; k < 8; ++k) idn[k] = csr[e + 8 + k];
        }
        #pragma unroll
        for (int k = 0; k < 8; ++k) {
            A0.x += bf_lo(v[k].x); A0.y += bf_hi(v[k].x);
            A1.x += bf_lo(v[k].y); A1.y += bf_hi(v[k].y);
            A2.x += bf_lo(v[k].z); A2.y += bf_hi(v[k].z);
            A3.x += bf_lo(v[k].w); A3.y += bf_hi(v[k].w);
        }
        if (r + 1 < nfull) {
            #pragma unroll
            for (int k = 0; k < 8; ++k) id[k] = idn[k];
        }
        e += 8;
    }
    if (e < d1) {                                // one masked 8-wide tail round
        const int last = d1 - 1;
        int   idt[8];
        float m[8];
        #pragma unroll
        for (int k = 0; k < 8; ++k) {
            const int ee = e + k;
            idt[k] = csr[(ee <= last) ? ee : last];
            m[k]   = (ee <= last) ? 1.0f : 0.0f;
        }
        uint4 v[8];
        #pragma unroll
        for (int k = 0; k < 8; ++k)
            v[k] = ((const uint4*)(fin + (size_t)idt[k] * DIM))[lx];
        #pragma unroll
        for (int k = 0; k < 8; ++k) {
            A0.x = fmaf(m[k], bf_lo(v[k].x), A0.x); A0.y = fmaf(m[k], bf_hi(v[k].x), A0.y);
            A1.x = fmaf(m[k], bf_lo(v[k].y), A1.x); A1.y = fmaf(m[k], bf_hi(v[k].y), A1.y);
            A2.x = fmaf(m[k], bf_lo(v[k].z), A2.x); A2.y = fmaf(m[k], bf_hi(v[k].z), A2.y);
            A3.x = fmaf(m[k], bf_lo(v[k].w), A3.x); A3.y = fmaf(m[k], bf_hi(v[k].w), A3.y);
        }
    }

    const float iv = 1.0f / (float)(deg + 1);
    uint4 p;
    p.x = pack_bf16(A0.x * iv, A0.y * iv);
    p.y = pack_bf16(A1.x * iv, A1.y * iv);
    p.z = pack_bf16(A2.x * iv, A2.y * iv);
    p.w = pack_bf16(A3.x * iv, A3.y * iv);
    ((uint4*)(xout + (size_t)slot * DIM))[lx] = p;
}

// ---------- MFMA dense: y = x_mean @ W^T (+b), LN, ELU ----------
// block = 256 threads (4 waves), 32 rows × 128 cols of output.
// C/D: col = lane&15, row = (lane>>4)*4 + reg   [measured m89]
template <bool OUT_BF16>
__global__ __launch_bounds__(256) void mgemm_kernel(
    const ushort* __restrict__ xin, void* __restrict__ fout,
    const ushort* __restrict__ wb, const float* __restrict__ bias,
    const float* __restrict__ gamma, const float* __restrict__ beta, int nrows)
{
    __shared__ float ys[32 * RST];
    const int t    = threadIdx.x;
    const int wave = t >> 6, lane = t & 63;
    const int rows = blockIdx.x * 32;
    const int row_off = (wave >> 1) * 16;
    const int col_off = (wave & 1) * 64;
    const int lm   = lane & 15;
    const int quad = lane >> 4;

    f32x4 acc[4] = {f32x4{0,0,0,0}, f32x4{0,0,0,0}, f32x4{0,0,0,0}, f32x4{0,0,0,0}};
    const ushort* __restrict__ xrow = xin + (size_t)(rows + row_off + lm) * DIM + quad * 8;
    const ushort* __restrict__ wrow = wb  + (size_t)(col_off + lm) * DIM + quad * 8;
    #pragma unroll
    for (int kk = 0; kk < 4; ++kk) {
        const bf16x8 a = __builtin_bit_cast(bf16x8, *(const u32x4*)(xrow + kk * 32));
        #pragma unroll
        for (int c = 0; c < 4; ++c) {
            const bf16x8 b = __builtin_bit_cast(bf16x8,
                *(const u32x4*)(wrow + (size_t)c * 16 * DIM + kk * 32));
            acc[c] = __builtin_amdgcn_mfma_f32_16x16x32_bf16(a, b, acc[c], 0, 0, 0);
        }
    }

    #pragma unroll
    for (int c = 0; c < 4; ++c) {
        #pragma unroll
        for (int r = 0; r < 4; ++r)
            ys[(row_off + quad * 4 + r) * RST + col_off + c * 16 + lm] = acc[c][r];
    }
    __syncthreads();

    // LN + ELU: 8 threads per row, 16 dims each
    {
        const int r   = t >> 3;              // row 0..31
        const int seg = t & 7;               // 0..7
        const int db  = seg * 16;
        const float* yr = ys + r * RST + db;
        float vs[16];
        #pragma unroll
        for (int q = 0; q < 4; ++q) {
            const float4 y4 = ((const float4*)yr)[q];
            const float4 b4 = ((const float4*)(bias + db))[q];
            vs[q * 4 + 0] = y4.x + b4.x;
            vs[q * 4 + 1] = y4.y + b4.y;
            vs[q * 4 + 2] = y4.z + b4.z;
            vs[q * 4 + 3] = y4.w + b4.w;
        }
        float s1 = 0.0f, s2 = 0.0f;
        #pragma unroll
        for (int i = 0; i < 16; ++i) { s1 += vs[i]; s2 += vs[i] * vs[i]; }
        #pragma unroll
        for (int m = 1; m < 8; m <<= 1) {
            s1 += __shfl_xor(s1, m);
            s2 += __shfl_xor(s2, m);
        }
        const float mu  = s1 * (1.0f / 128.0f);
        const float var = s2 * (1.0f / 128.0f) - mu * mu;
        const float rs  = rsqrtf(var + LN_EPS);
        float ov[16];
        #pragma unroll
        for (int q = 0; q < 4; ++q) {
            const float4 g4 = ((const float4*)(gamma + db))[q];
            const float4 t4 = ((const float4*)(beta + db))[q];
            float z;
            z = (vs[q*4+0] - mu) * rs * g4.x + t4.x; ov[q*4+0] = (z > 0.0f) ? z : expm1f(z);
            z = (vs[q*4+1] - mu) * rs * g4.y + t4.y; ov[q*4+1] = (z > 0.0f) ? z : expm1f(z);
            z = (vs[q*4+2] - mu) * rs * g4.z + t4.z; ov[q*4+2] = (z > 0.0f) ? z : expm1f(z);
            z = (vs[q*4+3] - mu) * rs * g4.w + t4.w; ov[q*4+3] = (z > 0.0f) ? z : expm1f(z);
        }
        const int n = rows + r;
        if (n < nrows) {
            if (OUT_BF16) {
                uint4 p0, p1;
                p0.x = pack_bf16(ov[0],  ov[1]);  p0.y = pack_bf16(ov[2],  ov[3]);
                p0.z = pack_bf16(ov[4],  ov[5]);  p0.w = pack_bf16(ov[6],  ov[7]);
                p1.x = pack_bf16(ov[8],  ov[9]);  p1.y = pack_bf16(ov[10], ov[11]);
                p1.z = pack_bf16(ov[12], ov[13]); p1.w = pack_bf16(ov[14], ov[15]);
                uint4* op = (uint4*)((ushort*)fout + (size_t)n * DIM + db);
                op[0] = p0;
                op[1] = p1;
            } else {
                float* op = (float*)fout + (size_t)n * DIM + db;
                ((float4*)op)[0] = make_float4(ov[0],  ov[1],  ov[2],  ov[3]);
                ((float4*)op)[1] = make_float4(ov[4],  ov[5],  ov[6],  ov[7]);
                ((float4*)op)[2] = make_float4(ov[8],  ov[9],  ov[10], ov[11]);
                ((float4*)op)[3] = make_float4(ov[12], ov[13], ov[14], ov[15]);
            }
        }
    }
}

extern "C" void kernel_launch(void* const* d_in, const int* in_sizes, int n_in,
                              void* d_out, int out_size, void* d_ws, size_t ws_size,
                              hipStream_t stream) {
    const float* emb   = (const float*)d_in[0];
    const float* W     = (const float*)d_in[1];
    const float* bias  = (const float*)d_in[2];
    const float* gamma = (const float*)d_in[3];
    const float* beta  = (const float*)d_in[4];
    const int*   src   = (const int*)d_in[5];
    const int*   dst   = (const int*)d_in[6];
    const int*   uid   = (const int*)d_in[7];

    // workspace layout (~55 MB)
    ushort* E    = (ushort*)d_ws;                     // 50000*128 bf16 (embedding)
    ushort* X    = E + (size_t)N_NODES * DIM;         // (50000+32)*128 bf16 (x_mean, padded)
    ushort* A    = X + (size_t)(N_NODES + 32) * DIM;  // 50000*128 bf16
    ushort* B    = A + (size_t)N_NODES * DIM;         // 50000*128 bf16
    ushort* WB   = B + (size_t)N_NODES * DIM;         // 3*128*128 bf16
    int*    cnt  = (int*)(WB + 3 * DIM * DIM);        // 50000
    int*    off  = cnt + N_NODES;                     // 50001 (+pad)
    int*    cur  = off + (N_NODES + 4);               // 50000
    int*    bsum = cur + N_NODES;                     // 256
    int*    bpre = bsum + 256;                        // 256
    int*    csr  = bpre + 256;                        // 800000

    hipMemsetAsync(cnt, 0, N_NODES * sizeof(int), stream);

    const int eblk4 = (N_EDGES / 4 + 255) / 256;      // 782
    const int nblk  = (N_NODES + 255) / 256;          // 196
    deg_kernel<<<eblk4, 256, 0, stream>>>(dst, cnt);
    scan1<<<nblk, 256, 0, stream>>>(cnt, off, bsum);
    scan2<<<1, 256, 0, stream>>>(bsum, bpre, nblk);
    scan3<<<nblk, 256, 0, stream>>>(off, bpre, cur);
    fill_kernel<<<eblk4, 256, 0, stream>>>(src, dst, cur, csr);
    cvt_kernel<<<(N_NODES * DIM / 4 + 255) / 256, 256, 0, stream>>>(emb, E);
    wcvt_kernel<<<(3 * DIM * DIM + 255) / 256, 256, 0, stream>>>(W, WB);

    const int gfull = (N_NODES + 31) / 32;            // 1563
    // layer 1
    agg_kernel<<<N_NODES / 16, 256, 0, stream>>>(E, X, off, csr, nullptr);
    mgemm_kernel<true><<<gfull, 256, 0, stream>>>(X, A, WB, bias, gamma, beta, N_NODES);
    // layer 2
    agg_kernel<<<N_NODES / 16, 256, 0, stream>>>(A, X, off, csr, nullptr);
    mgemm_kernel<true><<<gfull, 256, 0, stream>>>(X, B, WB + DIM * DIM, bias + DIM,
                                                  gamma + DIM, beta + DIM, N_NODES);
    // layer 3: only uid nodes are read — aggregate + transform just those
    agg_kernel<<<N_UID / 16, 256, 0, stream>>>(B, X, off, csr, uid);
    mgemm_kernel<false><<<N_UID / 32, 256, 0, stream>>>(X, (float*)d_out, WB + 2 * DIM * DIM,
                                                        bias + 2 * DIM, gamma + 2 * DIM,
                                                        beta + 2 * DIM, N_UID);
}